// Round 4
// baseline (192.673 us; speedup 1.0000x reference)
//
#include <hip/hip_runtime.h>
#include <math.h>

// input (32,3,128,128) f32; output (32,3,512,512) f32.
// loss = mean |bicubic_down4(output) - input|, 16-tap separable, symmetric pad 6.
#define BCN   96
#define IN_H  512
#define IN_W  512
#define OUT_H 128
#define OUT_W 128
#define TAPS  16
#define PAD   6
#define STRIDE 4
#define TOTAL_ELEMS (BCN * OUT_H * OUT_W)
#define INTER_BYTES ((size_t)BCN * IN_H * OUT_W * 4)   // 25,165,824

struct K16 { float w[TAPS]; };

__device__ __forceinline__ int sym_idx(int i, int n) {
    i = (i < 0) ? (-1 - i) : i;
    return (i >= n) ? (2 * n - 1 - i) : i;
}

// 3-bit XOR swizzle on the 16B-slot index (involution; keeps 16B alignment).
// Makes both the coalesced stage-write and the 32B-lane-stride window reads
// hit all bank-quads evenly (full-rank linear map on quad bits).
__device__ __forceinline__ int swz(int b) { return b ^ (((b >> 7) & 7) << 4); }

// ---------------- K1: horizontal conv, one wave per image row ----------------
__global__ __launch_bounds__(256)
void hconv_kernel(const float* __restrict__ outimg,  // (96,512,512)
                  float* __restrict__ inter,         // (96,512,128)
                  K16 kwa)
{
    __shared__ float rowbuf[4][IN_W];    // per-wave private 2KB regions
    const int tid = threadIdx.x;
    const int w   = tid >> 6;
    const int c   = tid & 63;            // col-pair (xo = 2c, 2c+1)
    const int gr  = blockIdx.x * 4 + w;  // global row 0..49151
    const int bc  = gr >> 9;
    const int y   = gr & 511;
    const float* row = outimg + ((size_t)bc * IN_H + y) * IN_W;

    char* lbase = reinterpret_cast<char*>(rowbuf[w]);
    {   // stage the row: 2 perfectly-coalesced float4 loads per lane
        const float4 a = reinterpret_cast<const float4*>(row)[c];
        const float4 b = reinterpret_cast<const float4*>(row)[c + 64];
        *reinterpret_cast<float4*>(lbase + swz(16 * c))        = a;
        *reinterpret_cast<float4*>(lbase + swz(1024 + 16 * c)) = b;
    }
    // wave-private region: no barrier needed, just drain LDS writes
    asm volatile("s_waitcnt lgkmcnt(0)" ::: "memory");

    int f0 = 8 * c - 8;                  // window start (float idx), 16B aligned
    f0 = (f0 < 0) ? 0 : (f0 > 488 ? 488 : f0);
    const int B0 = 4 * f0;
    const float4 w0 = *reinterpret_cast<const float4*>(lbase + swz(B0));
    const float4 w1 = *reinterpret_cast<const float4*>(lbase + swz(B0 + 16));
    const float4 w2 = *reinterpret_cast<const float4*>(lbase + swz(B0 + 32));
    const float4 w3 = *reinterpret_cast<const float4*>(lbase + swz(B0 + 48));
    const float4 w4 = *reinterpret_cast<const float4*>(lbase + swz(B0 + 64));
    const float4 w5 = *reinterpret_cast<const float4*>(lbase + swz(B0 + 80));
    const float win[24] = { w0.x,w0.y,w0.z,w0.w, w1.x,w1.y,w1.z,w1.w,
                            w2.x,w2.y,w2.z,w2.w, w3.x,w3.y,w3.z,w3.w,
                            w4.x,w4.y,w4.z,w4.w, w5.x,w5.y,w5.z,w5.w };
    float acc0 = 0.f, acc1 = 0.f;
    #pragma unroll
    for (int t = 0; t < TAPS; ++t) {
        acc0 += kwa.w[t] * win[t + 2];   // xo=2c  : row[8c-6+t]
        acc1 += kwa.w[t] * win[t + 6];   // xo=2c+1: row[8c-2+t]
    }
    if (c == 0) {            // f0=0: win[i] = col i  (verified in rounds 2-3)
        float a0 = 0.f, a1 = 0.f;
        #pragma unroll
        for (int t = 0; t < TAPS; ++t) {
            const int i0 = (t < 6) ? (5 - t) : (t - 6);
            const int i1 = (t < 2) ? (1 - t) : (t - 2);
            a0 += kwa.w[t] * win[i0];
            a1 += kwa.w[t] * win[i1];
        }
        acc0 = a0; acc1 = a1;
    } else if (c == 63) {    // f0=488: win[i] = col 488+i
        float a0 = 0.f, a1 = 0.f;
        #pragma unroll
        for (int t = 0; t < TAPS; ++t) {
            const int i0 = (t <= 13) ? (10 + t) : ((t == 14) ? 23 : 22);
            const int i1 = (t <= 9) ? (14 + t) : (33 - t);
            a0 += kwa.w[t] * win[i0];
            a1 += kwa.w[t] * win[i1];
        }
        acc0 = a0; acc1 = a1;
    }
    reinterpret_cast<float2*>(inter + ((size_t)bc * IN_H + y) * OUT_W)[c] =
        make_float2(acc0, acc1);
}

// -------- K2: vertical conv + |diff| + reduction, 2 outputs per thread -------
__global__ __launch_bounds__(256)
void vconv_kernel(const float* __restrict__ inter,   // (96,512,128)
                  const float* __restrict__ input,   // (96,128,128)
                  float* __restrict__ loss, K16 kwa)
{
    __shared__ float wsum[4];
    const int tid = threadIdx.x;
    const int bc  = blockIdx.x >> 5;     // 96 channels
    const int rq  = blockIdx.x & 31;     // row-quad
    const int c   = tid & 63;            // col-pair
    const int yl  = tid >> 6;            // 0..3 (wave-uniform)
    const int yo  = rq * 4 + yl;
    const float* src = inter + (size_t)bc * IN_H * OUT_W;

    float a0 = 0.f, a1 = 0.f;
    const int ybase = STRIDE * yo - PAD;
    #pragma unroll
    for (int t = 0; t < TAPS; ++t) {
        const int r = sym_idx(ybase + t, IN_H);
        const float2 v = reinterpret_cast<const float2*>(src + (size_t)r * OUT_W)[c];
        a0 += kwa.w[t] * v.x;
        a1 += kwa.w[t] * v.y;
    }
    const float2 ref =
        reinterpret_cast<const float2*>(input + ((size_t)bc * OUT_H + yo) * OUT_W)[c];
    float lsum = fabsf(a0 - ref.x) + fabsf(a1 - ref.y);

    #pragma unroll
    for (int off = 32; off > 0; off >>= 1)
        lsum += __shfl_down(lsum, off, 64);
    const int wid = tid >> 6, lane = tid & 63;
    if (lane == 0) wsum[wid] = lsum;
    __syncthreads();
    if (tid == 0) {
        const float s = wsum[0] + wsum[1] + wsum[2] + wsum[3];
        atomicAdd(loss, s * (1.0f / (float)TOTAL_ELEMS));
    }
}

// ----------- fallback (round-3 verified single-kernel), if ws too small -----
#define TR    8
#define IR    ((TR - 1) * STRIDE + TAPS)
#define NCH   (IR / 4)
#define NBLK  (BCN * (OUT_H / TR))

__device__ __forceinline__ int swz1(int b) { return b ^ (((b >> 7) & 1) << 4); }

__global__ __launch_bounds__(256)
void bploss_fallback(const float* __restrict__ input,
                     const float* __restrict__ outimg,
                     float* __restrict__ loss, K16 kwa)
{
    __shared__ float dbuf[2][4 * IN_W];
    __shared__ float hrow[4][OUT_W];
    __shared__ float kwl[TAPS];
    __shared__ float wsum[4];

    const int tid  = threadIdx.x;
    const int bc   = blockIdx.x >> 4;
    const int tile = blockIdx.x & 15;
    const int r0   = tile * TR;
    const int iy0  = r0 * STRIDE - PAD;
    const float* img = outimg + (size_t)bc * IN_H * IN_W;

    auto gsrc = [&](int ch, int s) -> const float4* {
        const int y = sym_idx(iy0 + ch * 4 + (s >> 7), IN_H);
        return reinterpret_cast<const float4*>(img + (size_t)y * IN_W + (s & 127) * 4);
    };
    auto lslot = [&](float* buf, int s) -> float4* {
        return reinterpret_cast<float4*>(reinterpret_cast<char*>(buf) + swz1(s << 4));
    };
    {
        float4 a = *gsrc(0, tid);
        float4 b = *gsrc(0, tid + 256);
        *lslot(dbuf[0], tid)       = a;
        *lslot(dbuf[0], tid + 256) = b;
    }
    if (tid < TAPS) kwl[tid] = kwa.w[tid];
    __syncthreads();

    const int pr = tid >> 6;
    const int c  = tid & 63;
    const int vb = tid >> 7;
    const int vx = tid & 127;
    int f0 = 8 * c - 8;
    f0 = (f0 < 0) ? 0 : (f0 > 488 ? 488 : f0);
    const int Lbase = pr * (IN_W * 4) + f0 * 4;
    float vacc[4] = {0.f, 0.f, 0.f, 0.f};

    for (int ch = 0; ch < NCH; ++ch) {
        const int chn = (ch + 1 < NCH) ? (ch + 1) : (NCH - 1);
        const float4 n0 = *gsrc(chn, tid);
        const float4 n1 = *gsrc(chn, tid + 256);
        const char* raw = reinterpret_cast<const char*>(dbuf[ch & 1]);
        const float4 w0 = *reinterpret_cast<const float4*>(raw + swz1(Lbase));
        const float4 w1 = *reinterpret_cast<const float4*>(raw + swz1(Lbase + 16));
        const float4 w2 = *reinterpret_cast<const float4*>(raw + swz1(Lbase + 32));
        const float4 w3 = *reinterpret_cast<const float4*>(raw + swz1(Lbase + 48));
        const float4 w4 = *reinterpret_cast<const float4*>(raw + swz1(Lbase + 64));
        const float4 w5 = *reinterpret_cast<const float4*>(raw + swz1(Lbase + 80));
        const float win[24] = { w0.x,w0.y,w0.z,w0.w, w1.x,w1.y,w1.z,w1.w,
                                w2.x,w2.y,w2.z,w2.w, w3.x,w3.y,w3.z,w3.w,
                                w4.x,w4.y,w4.z,w4.w, w5.x,w5.y,w5.z,w5.w };
        float acc0 = 0.f, acc1 = 0.f;
        #pragma unroll
        for (int t = 0; t < TAPS; ++t) {
            acc0 += kwa.w[t] * win[t + 2];
            acc1 += kwa.w[t] * win[t + 6];
        }
        if (c == 0) {
            float a0 = 0.f, a1 = 0.f;
            #pragma unroll
            for (int t = 0; t < TAPS; ++t) {
                const int i0 = (t < 6) ? (5 - t) : (t - 6);
                const int i1 = (t < 2) ? (1 - t) : (t - 2);
                a0 += kwa.w[t] * win[i0];
                a1 += kwa.w[t] * win[i1];
            }
            acc0 = a0; acc1 = a1;
        } else if (c == 63) {
            float a0 = 0.f, a1 = 0.f;
            #pragma unroll
            for (int t = 0; t < TAPS; ++t) {
                const int i0 = (t <= 13) ? (10 + t) : ((t == 14) ? 23 : 22);
                const int i1 = (t <= 9) ? (14 + t) : (33 - t);
                a0 += kwa.w[t] * win[i0];
                a1 += kwa.w[t] * win[i1];
            }
            acc0 = a0; acc1 = a1;
        }
        *reinterpret_cast<float2*>(&hrow[pr][2 * c]) = make_float2(acc0, acc1);
        __syncthreads();
        const float h0 = hrow[0][vx], h1 = hrow[1][vx],
                    h2 = hrow[2][vx], h3 = hrow[3][vx];
        #pragma unroll
        for (int k = 0; k < 4; ++k) {
            const int t0 = 4 * (ch - (4 * vb + k));
            if (t0 >= 0 && t0 < TAPS) {
                vacc[k] += kwl[t0] * h0 + kwl[t0 + 1] * h1
                         + kwl[t0 + 2] * h2 + kwl[t0 + 3] * h3;
            }
        }
        *lslot(dbuf[(ch + 1) & 1], tid)       = n0;
        *lslot(dbuf[(ch + 1) & 1], tid + 256) = n1;
        __syncthreads();
    }

    float lsum = 0.f;
    #pragma unroll
    for (int k = 0; k < 4; ++k) {
        const int yo = r0 + 4 * vb + k;
        const float ref = input[((size_t)bc * OUT_H + yo) * OUT_W + vx];
        lsum += fabsf(vacc[k] - ref);
    }
    #pragma unroll
    for (int off = 32; off > 0; off >>= 1)
        lsum += __shfl_down(lsum, off, 64);
    const int wid = tid >> 6, lane = tid & 63;
    if (lane == 0) wsum[wid] = lsum;
    __syncthreads();
    if (tid == 0) {
        const float s = wsum[0] + wsum[1] + wsum[2] + wsum[3];
        atomicAdd(loss, s * (1.0f / (float)TOTAL_ELEMS));
    }
}

static void make_weights(K16* kw) {
    const double scale = 0.25;
    double w[TAPS]; double s = 0.0;
    for (int t = 0; t < TAPS; ++t) {
        const double ax = fabs((7.5 - (double)t) * scale);
        double v;
        if (ax <= 1.0)      v = 1.5 * ax * ax * ax - 2.5 * ax * ax + 1.0;
        else if (ax <= 2.0) v = -0.5 * ax * ax * ax + 2.5 * ax * ax - 4.0 * ax + 2.0;
        else                v = 0.0;
        w[t] = v * scale; s += w[t];
    }
    for (int t = 0; t < TAPS; ++t) kw->w[t] = (float)(w[t] / s);
}

extern "C" void kernel_launch(void* const* d_in, const int* in_sizes, int n_in,
                              void* d_out, int out_size, void* d_ws, size_t ws_size,
                              hipStream_t stream) {
    const float* input;
    const float* outimg;
    if (in_sizes[0] == TOTAL_ELEMS) {
        input  = (const float*)d_in[0];
        outimg = (const float*)d_in[1];
    } else {
        input  = (const float*)d_in[1];
        outimg = (const float*)d_in[0];
    }
    float* loss = (float*)d_out;

    K16 kw;
    make_weights(&kw);

    hipMemsetAsync(d_out, 0, sizeof(float), stream);
    if (ws_size >= INTER_BYTES) {
        float* inter = (float*)d_ws;
        hconv_kernel<<<BCN * IN_H / 4, 256, 0, stream>>>(outimg, inter, kw);
        vconv_kernel<<<BCN * (OUT_H / 4), 256, 0, stream>>>(inter, input, loss, kw);
    } else {
        bploss_fallback<<<NBLK, 256, 0, stream>>>(input, outimg, loss, kw);
    }
}

// Round 5
// 169.157 us; speedup vs baseline: 1.1390x; 1.1390x over previous
//
#include <hip/hip_runtime.h>
#include <math.h>

// input (32,3,128,128) f32; output (32,3,512,512) f32.
// loss = mean |bicubic_down4(output) - input|, 16-tap separable, symmetric pad 6.
#define BCN   96
#define IN_H  512
#define IN_W  512
#define OUT_H 128
#define OUT_W 128
#define TAPS  16
#define PAD   6
#define STRIDE 4
#define TR    8
#define IR    ((TR - 1) * STRIDE + TAPS)   // 44 rows
#define NCH   (IR / 4)                     // 11 chunks of 4 rows
#define NBLK  (BCN * (OUT_H / TR))         // 1536 blocks
#define TOTAL_ELEMS (BCN * OUT_H * OUT_W)

struct K16 { float w[TAPS]; };

__device__ __forceinline__ int sym_idx(int i, int n) {
    i = (i < 0) ? (-1 - i) : i;
    return (i >= n) ? (2 * n - 1 - i) : i;
}

// XOR-swizzle (involution) on 16B slots: spreads 32B-lane-stride ds_read_b128.
__device__ __forceinline__ int swz1(int b) { return b ^ (((b >> 7) & 1) << 4); }

__global__ __launch_bounds__(256)
void bploss_kernel(const float* __restrict__ input,
                   const float* __restrict__ outimg,
                   float* __restrict__ loss, K16 kwa)
{
    __shared__ float dbuf[2][4 * IN_W];   // 2 x 8 KB rolling chunk buffers
    __shared__ float hrow[2][4][OUT_W];   // 2 x 2 KB h-conv results
    __shared__ float kwl[TAPS];
    __shared__ float wsum[4];

    const int tid  = threadIdx.x;
    const int bc   = blockIdx.x >> 4;
    const int tile = blockIdx.x & 15;
    const int r0   = tile * TR;
    const int iy0  = r0 * STRIDE - PAD;
    const float* img = outimg + (size_t)bc * IN_H * IN_W;

    // chunk ch, slot s in [0,512): row s>>7 of chunk, float col (s&127)*4
    auto gsrc = [&](int ch, int s) -> const float4* {
        const int y = sym_idx(iy0 + ch * 4 + (s >> 7), IN_H);
        return reinterpret_cast<const float4*>(img + (size_t)y * IN_W + (s & 127) * 4);
    };
    auto lslot = [&](float* buf, int s) -> float4* {
        return reinterpret_cast<float4*>(reinterpret_cast<char*>(buf) + swz1(s << 4));
    };

    if (tid < TAPS) kwl[tid] = kwa.w[tid];

    // ---- 4-deep register prefetch pipeline ----
    // rA/rB[slot] hold chunk (slot = ch & 3). Issue loads 3 chunks ahead;
    // compiler's auto vmcnt waits (on first reg use) give counted waits —
    // no vmcnt(0) drain because we use RAW s_barrier, not __syncthreads.
    float4 rA[4], rB[4];
    #pragma unroll
    for (int c0 = 0; c0 < 3; ++c0) {      // issue chunks 0,1,2 back-to-back
        rA[c0] = *gsrc(c0, tid);
        rB[c0] = *gsrc(c0, tid + 256);
    }
    // stage chunk 0 into dbuf[0] (waits only chunk-0's loads)
    *lslot(dbuf[0], tid)       = rA[0];
    *lslot(dbuf[0], tid + 256) = rB[0];
    asm volatile("s_waitcnt lgkmcnt(0)" ::: "memory");
    __builtin_amdgcn_s_barrier();
    __builtin_amdgcn_sched_barrier(0);

    const int pr = tid >> 6;              // h-conv: raw row in chunk
    const int c  = tid & 63;              // h-conv: col-pair (xo=2c,2c+1)
    const int vb = tid >> 7;              // v-accum: row-group
    const int vx = tid & 127;             // v-accum: column
    int f0 = 8 * c - 8;
    f0 = (f0 < 0) ? 0 : (f0 > 488 ? 488 : f0);
    const int Lbase = pr * (IN_W * 4) + f0 * 4;
    float vacc[4] = {0.f, 0.f, 0.f, 0.f};

    #pragma unroll
    for (int i = 0; i < NCH; ++i) {       // fully unrolled: all indices static
        // issue chunk i+3's loads (deepest point of the pipeline)
        if (i + 3 < NCH) {
            rA[(i + 3) & 3] = *gsrc(i + 3, tid);
            rB[(i + 3) & 3] = *gsrc(i + 3, tid + 256);
        }

        // h-conv of chunk i from dbuf[i&1] (swizzled ds_read_b128)
        const char* raw = reinterpret_cast<const char*>(dbuf[i & 1]);
        const float4 w0 = *reinterpret_cast<const float4*>(raw + swz1(Lbase));
        const float4 w1 = *reinterpret_cast<const float4*>(raw + swz1(Lbase + 16));
        const float4 w2 = *reinterpret_cast<const float4*>(raw + swz1(Lbase + 32));
        const float4 w3 = *reinterpret_cast<const float4*>(raw + swz1(Lbase + 48));
        const float4 w4 = *reinterpret_cast<const float4*>(raw + swz1(Lbase + 64));
        const float4 w5 = *reinterpret_cast<const float4*>(raw + swz1(Lbase + 80));
        const float win[24] = { w0.x,w0.y,w0.z,w0.w, w1.x,w1.y,w1.z,w1.w,
                                w2.x,w2.y,w2.z,w2.w, w3.x,w3.y,w3.z,w3.w,
                                w4.x,w4.y,w4.z,w4.w, w5.x,w5.y,w5.z,w5.w };
        float acc0 = 0.f, acc1 = 0.f;
        #pragma unroll
        for (int t = 0; t < TAPS; ++t) {
            acc0 += kwa.w[t] * win[t + 2];
            acc1 += kwa.w[t] * win[t + 6];
        }
        if (c == 0) {          // f0=0: win[k] = col k (verified r2-r4)
            float a0 = 0.f, a1 = 0.f;
            #pragma unroll
            for (int t = 0; t < TAPS; ++t) {
                const int i0 = (t < 6) ? (5 - t) : (t - 6);
                const int i1 = (t < 2) ? (1 - t) : (t - 2);
                a0 += kwa.w[t] * win[i0];
                a1 += kwa.w[t] * win[i1];
            }
            acc0 = a0; acc1 = a1;
        } else if (c == 63) {  // f0=488: win[k] = col 488+k
            float a0 = 0.f, a1 = 0.f;
            #pragma unroll
            for (int t = 0; t < TAPS; ++t) {
                const int i0 = (t <= 13) ? (10 + t) : ((t == 14) ? 23 : 22);
                const int i1 = (t <= 9) ? (14 + t) : (33 - t);
                a0 += kwa.w[t] * win[i0];
                a1 += kwa.w[t] * win[i1];
            }
            acc0 = a0; acc1 = a1;
        }
        *reinterpret_cast<float2*>(&hrow[i & 1][pr][2 * c]) = make_float2(acc0, acc1);

        // stage chunk i+1 into dbuf[(i+1)&1] (regs issued at iter i-2:
        // compiler emits a counted vmcnt wait for exactly these two regs)
        if (i + 1 < NCH) {
            *lslot(dbuf[(i + 1) & 1], tid)       = rA[(i + 1) & 3];
            *lslot(dbuf[(i + 1) & 1], tid + 256) = rB[(i + 1) & 3];
        }

        // one raw barrier per chunk: publishes hrow[i&1] + dbuf[(i+1)&1];
        // protects dbuf[i&1] (my ds_reads already drained by data deps).
        asm volatile("s_waitcnt lgkmcnt(0)" ::: "memory");
        __builtin_amdgcn_s_barrier();
        __builtin_amdgcn_sched_barrier(0);

        // v-accum from hrow[i&1]: chunk i = taps 4*(i-yl) .. +3 for yl=4*vb+k
        const float h0 = hrow[i & 1][0][vx], h1 = hrow[i & 1][1][vx],
                    h2 = hrow[i & 1][2][vx], h3 = hrow[i & 1][3][vx];
        #pragma unroll
        for (int k = 0; k < 4; ++k) {
            const int t0 = 4 * (i - (4 * vb + k));   // wave-uniform
            if (t0 >= 0 && t0 < TAPS) {
                vacc[k] += kwl[t0] * h0 + kwl[t0 + 1] * h1
                         + kwl[t0 + 2] * h2 + kwl[t0 + 3] * h3;
            }
        }
    }

    // ---- epilogue: |diff| + reduction ----
    float lsum = 0.f;
    #pragma unroll
    for (int k = 0; k < 4; ++k) {
        const int yo = r0 + 4 * vb + k;
        const float ref = input[((size_t)bc * OUT_H + yo) * OUT_W + vx];
        lsum += fabsf(vacc[k] - ref);
    }
    #pragma unroll
    for (int off = 32; off > 0; off >>= 1)
        lsum += __shfl_down(lsum, off, 64);
    const int wid = tid >> 6, lane = tid & 63;
    if (lane == 0) wsum[wid] = lsum;
    __syncthreads();
    if (tid == 0) {
        const float s = wsum[0] + wsum[1] + wsum[2] + wsum[3];
        atomicAdd(loss, s * (1.0f / (float)TOTAL_ELEMS));
    }
}

static void make_weights(K16* kw) {
    const double scale = 0.25;
    double w[TAPS]; double s = 0.0;
    for (int t = 0; t < TAPS; ++t) {
        const double ax = fabs((7.5 - (double)t) * scale);
        double v;
        if (ax <= 1.0)      v = 1.5 * ax * ax * ax - 2.5 * ax * ax + 1.0;
        else if (ax <= 2.0) v = -0.5 * ax * ax * ax + 2.5 * ax * ax - 4.0 * ax + 2.0;
        else                v = 0.0;
        w[t] = v * scale; s += w[t];
    }
    for (int t = 0; t < TAPS; ++t) kw->w[t] = (float)(w[t] / s);
}

extern "C" void kernel_launch(void* const* d_in, const int* in_sizes, int n_in,
                              void* d_out, int out_size, void* d_ws, size_t ws_size,
                              hipStream_t stream) {
    const float* input;
    const float* outimg;
    if (in_sizes[0] == TOTAL_ELEMS) {
        input  = (const float*)d_in[0];
        outimg = (const float*)d_in[1];
    } else {
        input  = (const float*)d_in[1];
        outimg = (const float*)d_in[0];
    }
    float* loss = (float*)d_out;

    K16 kw;
    make_weights(&kw);

    hipMemsetAsync(d_out, 0, sizeof(float), stream);
    bploss_kernel<<<NBLK, 256, 0, stream>>>(input, outimg, loss, kw);
}